// Round 3
// baseline (457.661 us; speedup 1.0000x reference)
//
#include <hip/hip_runtime.h>
#include <cstdint>

// CrossViewBlockTransformer on MI355X (gfx950), round 3.
// One wave per 4x4 image block; wave-private LDS; no barriers.
// All matmuls via v_mfma_f32_16x16x16_bf16 with same-lane accumulator reuse:
//   q/k accumulators -> energy A/B frags; v accumulator -> PV A frag;
//   PV accumulator -> FC B frag. Only the 16x16 attn matrix goes through LDS.
// Weights packed to frag-ordered bf16 (hi+lo for Wq/Wk) in a __device__
// global by a prep kernel, preloaded into registers before the block loop.
// X_r is consumed only as B-frags -> loaded directly from global in frag
// layout (no LDS staging). sXq stages X_q for frags + residual + transpose.

typedef float  f4    __attribute__((ext_vector_type(4)));
typedef float  f32x4 __attribute__((ext_vector_type(4)));
typedef short  s16x4 __attribute__((ext_vector_type(4)));
typedef unsigned short u16;
typedef __bf16 bf16;

#define MFMA(a,b,c) __builtin_amdgcn_mfma_f32_16x16x16bf16_1k((a),(b),(c),0,0,0)

// packs: 0=Wq_hi 1=Wq_lo 2=Wk_hi 3=Wk_lo 4=Wv_hi 5=Wfc_hi
__device__ __align__(16) u16 g_wpack[6 * 4096];

__device__ __forceinline__ u16 bfbits(float x) {
  return __builtin_bit_cast(u16, (bf16)x);
}

// frag[tile=a*4+b][lane][j] = W[16a + (lane&15)][16b + 4*(lane>>4) + j]
__global__ void prep_w(const float* __restrict__ Wq, const float* __restrict__ Wk,
                       const float* __restrict__ Wv, const float* __restrict__ Wfc)
{
  const int t = threadIdx.x;  // 256 threads
  for (int e = t; e < 1024; e += 256) {
    const int tile = e >> 6, l = e & 63;
    const int row = 16 * (tile >> 2) + (l & 15);
    const int col = 16 * (tile & 3) + 4 * (l >> 4);
#pragma unroll
    for (int j = 0; j < 4; ++j) {
      float wq = Wq[row * 64 + col + j]; bf16 hq = (bf16)wq;
      g_wpack[0 * 4096 + e * 4 + j] = __builtin_bit_cast(u16, hq);
      g_wpack[1 * 4096 + e * 4 + j] = bfbits(wq - (float)hq);
      float wk = Wk[row * 64 + col + j]; bf16 hk = (bf16)wk;
      g_wpack[2 * 4096 + e * 4 + j] = __builtin_bit_cast(u16, hk);
      g_wpack[3 * 4096 + e * 4 + j] = bfbits(wk - (float)hk);
      g_wpack[4 * 4096 + e * 4 + j] = bfbits(Wv[row * 64 + col + j]);
      g_wpack[5 * 4096 + e * 4 + j] = bfbits(Wfc[row * 64 + col + j]);
    }
  }
}

__global__ void __launch_bounds__(64, 4)
cvbt3(const float* __restrict__ qx, const float* __restrict__ rx,
      const float* __restrict__ gw, const float* __restrict__ gb,
      float* __restrict__ out)
{
  __shared__ float sXq[64 * 20];   // X_q [c][pix], stride 20 dwords (5120 B)
  __shared__ u16   sP [16 * 20];   // attn [n'][m'] bf16               (640 B)
  __shared__ float sGn[128];       // gamma | beta                     (512 B)

  const int lane = threadIdx.x;
  const int n = lane & 15;   // col index within a 16-tile
  const int g = lane >> 4;   // 4-row group

  sGn[lane]      = gw[lane];
  sGn[64 + lane] = gb[lane];

  // ---- preload all weight fragments into registers ----
  s16x4 Wqh[4][4], Wql[4][4], Wkh[4][4], Wkl[4][4], Wvh[4][4], Wfh[4][4];
#pragma unroll
  for (int a = 0; a < 4; ++a)
#pragma unroll
    for (int c = 0; c < 4; ++c) {
      const int idx = (a * 4 + c) * 256 + lane * 4;
      Wqh[a][c] = *(const s16x4*)&g_wpack[0 * 4096 + idx];
      Wql[a][c] = *(const s16x4*)&g_wpack[1 * 4096 + idx];
      Wkh[a][c] = *(const s16x4*)&g_wpack[2 * 4096 + idx];
      Wkl[a][c] = *(const s16x4*)&g_wpack[3 * 4096 + idx];
      Wvh[a][c] = *(const s16x4*)&g_wpack[4 * 4096 + idx];
      Wfh[a][c] = *(const s16x4*)&g_wpack[5 * 4096 + idx];
    }

  // XCD-aware swizzle (grid fixed at 8192 = 8 * 1024)
  const int bid = blockIdx.x;
  const int wid = (bid & 7) * 1024 + (bid >> 3);

  const f32x4 zero = {0.f, 0.f, 0.f, 0.f};

#pragma unroll 1
  for (int nb = wid; nb < 32768; nb += 8192) {
    const uint32_t b  = (uint32_t)nb >> 12;
    const uint32_t hb = ((uint32_t)nb >> 6) & 63;
    const uint32_t wb = (uint32_t)nb & 63;
    const uint32_t blockoff = b * 4194304u + hb * 1024u + wb * 4u;
    const uint32_t qbase = blockoff + (uint32_t)lane * 65536u;

    // ---- stage X_q (lane = channel), b128 to LDS ----
    f4 vq[4];
#pragma unroll
    for (int i = 0; i < 4; ++i) vq[i] = *(const f4*)(qx + qbase + i * 256u);
#pragma unroll
    for (int i = 0; i < 4; ++i) *(f4*)&sXq[20 * lane + 4 * i] = vq[i];

    // ---- X_q B-frags (hi/lo) from LDS transpose read ----
    s16x4 fqh[4], fql[4];
#pragma unroll
    for (int kt = 0; kt < 4; ++kt)
#pragma unroll
      for (int j = 0; j < 4; ++j) {
        float x1 = sXq[20 * (16 * kt + 4 * g + j) + n];
        bf16 h = (bf16)x1;
        fqh[kt][j] = (short)__builtin_bit_cast(u16, h);
        fql[kt][j] = (short)bfbits(x1 - (float)h);
      }

    // ---- X_r B-frags (hi/lo) directly from global ----
    const uint32_t rbase = blockoff + (uint32_t)(4 * g) * 65536u +
                           (uint32_t)((n >> 2) * 256 + (n & 3));
    s16x4 frh[4], frl[4];
#pragma unroll
    for (int kt = 0; kt < 4; ++kt)
#pragma unroll
      for (int j = 0; j < 4; ++j) {
        float x2 = rx[rbase + (uint32_t)((16 * kt + j) * 65536)];
        bf16 h = (bf16)x2;
        frh[kt][j] = (short)__builtin_bit_cast(u16, h);
        frl[kt][j] = (short)bfbits(x2 - (float)h);
      }

    // ---- q = Wq*X_q, k = Wk*X_r  (Wh*Xh + Wh*Xl + Wl*Xh) ----
    f32x4 aq[4], ak[4];
#pragma unroll
    for (int mt = 0; mt < 4; ++mt) { aq[mt] = zero; ak[mt] = zero; }
#pragma unroll
    for (int mt = 0; mt < 4; ++mt)
#pragma unroll
      for (int kt = 0; kt < 4; ++kt) {
        aq[mt] = MFMA(Wqh[mt][kt], fqh[kt], aq[mt]);
        aq[mt] = MFMA(Wqh[mt][kt], fql[kt], aq[mt]);
        aq[mt] = MFMA(Wql[mt][kt], fqh[kt], aq[mt]);
        ak[mt] = MFMA(Wkh[mt][kt], frh[kt], ak[mt]);
        ak[mt] = MFMA(Wkh[mt][kt], frl[kt], ak[mt]);
        ak[mt] = MFMA(Wkl[mt][kt], frh[kt], ak[mt]);
      }
    // aq[mt][r] = q[16mt+4g+r][n]; ak likewise.

    // ---- v^T tiles: A = X_r frag, B = Wv frag -> av[nt][r] = v[16nt+n][4g+r]
    f32x4 av[4];
#pragma unroll
    for (int nt = 0; nt < 4; ++nt) {
      av[nt] = zero;
#pragma unroll
      for (int kt = 0; kt < 4; ++kt) av[nt] = MFMA(frh[kt], Wvh[nt][kt], av[nt]);
    }

    // ---- split q,k accumulators (energy frags, same lane) ----
    s16x4 qh[4], ql[4], kh[4], kl[4];
#pragma unroll
    for (int kt = 0; kt < 4; ++kt)
#pragma unroll
      for (int r = 0; r < 4; ++r) {
        bf16 h = (bf16)aq[kt][r];
        qh[kt][r] = (short)__builtin_bit_cast(u16, h);
        ql[kt][r] = (short)bfbits(aq[kt][r] - (float)h);
        bf16 h2 = (bf16)ak[kt][r];
        kh[kt][r] = (short)__builtin_bit_cast(u16, h2);
        kl[kt][r] = (short)bfbits(ak[kt][r] - (float)h2);
      }

    // ---- energy = q^T k : e[r] = E[qpix=4g+r][refpix=n] ----
    f32x4 e = zero;
#pragma unroll
    for (int kt = 0; kt < 4; ++kt) {
      e = MFMA(qh[kt], kh[kt], e);
      e = MFMA(qh[kt], kl[kt], e);
      e = MFMA(ql[kt], kh[kt], e);
    }

    // ---- softmax over refpix (across the 16-lane groups) ----
#pragma unroll
    for (int r = 0; r < 4; ++r) {
      float x = e[r];
      float m = x;
      m = fmaxf(m, __shfl_xor(m, 1));
      m = fmaxf(m, __shfl_xor(m, 2));
      m = fmaxf(m, __shfl_xor(m, 4));
      m = fmaxf(m, __shfl_xor(m, 8));
      float p = __expf(x - m);
      float s = p;
      s += __shfl_xor(s, 1);
      s += __shfl_xor(s, 2);
      s += __shfl_xor(s, 4);
      s += __shfl_xor(s, 8);
      sP[(4 * g + r) * 20 + n] = bfbits(p * __builtin_amdgcn_rcpf(s));
    }

    // ---- O tiles: A = v (av, same lane), B = attn^T (LDS transpose) ----
    s16x4 pa = *(const s16x4*)&sP[n * 20 + 4 * g];  // attn[n][4g+j]
    f32x4 ao[4];
#pragma unroll
    for (int mt = 0; mt < 4; ++mt) {
      s16x4 vb;
#pragma unroll
      for (int j = 0; j < 4; ++j) vb[j] = (short)bfbits(av[mt][j]);
      ao[mt] = MFMA(vb, pa, zero);   // ao[mt][r] = O[16mt+4g+r][n]
    }

    // ---- x = Wfc * O : B-frag = ao as bf16 (same lane) ----
    s16x4 ob[4];
#pragma unroll
    for (int kt = 0; kt < 4; ++kt)
#pragma unroll
      for (int j = 0; j < 4; ++j) ob[kt][j] = (short)bfbits(ao[kt][j]);
    f32x4 xa[4];
#pragma unroll
    for (int mt = 0; mt < 4; ++mt) {
      xa[mt] = zero;
#pragma unroll
      for (int kt = 0; kt < 4; ++kt) xa[mt] = MFMA(Wfh[mt][kt], ob[kt], xa[mt]);
    }

    // ---- GroupNorm over 64x16 (fp32) ----
    float s1 = 0.f, s2 = 0.f;
#pragma unroll
    for (int mt = 0; mt < 4; ++mt)
#pragma unroll
      for (int r = 0; r < 4; ++r) {
        float v = xa[mt][r];
        s1 += v; s2 += v * v;
      }
#pragma unroll
    for (int mask = 1; mask < 64; mask <<= 1) {
      s1 += __shfl_xor(s1, mask);
      s2 += __shfl_xor(s2, mask);
    }
    const float mean = s1 * (1.f / 1024.f);
    const float var  = s2 * (1.f / 1024.f) - mean * mean;
    const float rstd = rsqrtf(var + 1e-5f);

    // ---- affine + exact fp32 residual, written back into sXq ----
#pragma unroll
    for (int mt = 0; mt < 4; ++mt)
#pragma unroll
      for (int r = 0; r < 4; ++r) {
        const int row = 16 * mt + 4 * g + r;
        float q0 = sXq[20 * row + n];
        sXq[20 * row + n] =
            (xa[mt][r] - mean) * rstd * sGn[row] + sGn[64 + row] + q0;
      }

    // ---- transpose-out, 16B coalesced-per-lane stores ----
#pragma unroll
    for (int i = 0; i < 4; ++i) {
      f4 o = *(const f4*)&sXq[20 * lane + 4 * i];
      *(f4*)(out + qbase + i * 256u) = o;
    }
  }
}

extern "C" void kernel_launch(void* const* d_in, const int* in_sizes, int n_in,
                              void* d_out, int out_size, void* d_ws, size_t ws_size,
                              hipStream_t stream) {
  const float* qx  = (const float*)d_in[0];
  const float* rx  = (const float*)d_in[1];
  const float* Wq  = (const float*)d_in[2];
  const float* Wk  = (const float*)d_in[3];
  const float* Wv  = (const float*)d_in[4];
  const float* Wfc = (const float*)d_in[5];
  const float* gw  = (const float*)d_in[6];
  const float* gb  = (const float*)d_in[7];
  float* out = (float*)d_out;

  prep_w<<<dim3(1), dim3(256), 0, stream>>>(Wq, Wk, Wv, Wfc);
  // grid fixed at 8192 (matches the swizzle constant); 4 blocks per wave
  cvbt3<<<dim3(8192), dim3(64), 0, stream>>>(qx, rx, gw, gb, out);
}

// Round 4
// 213.678 us; speedup vs baseline: 2.1418x; 2.1418x over previous
//
#include <hip/hip_runtime.h>
#include <cstdint>

// CrossViewBlockTransformer on MI355X (gfx950), round 4.
// WG = 256 threads (4 waves) handles a strip of 4 horizontally-adjacent 4x4
// blocks: cooperative, fully-coalesced 64B-line loads/stores via swizzled LDS.
// Each wave computes one block; waves own disjoint pixel-column slices of the
// LDS strip, so only 3 barriers per strip. Weights live in a __device__ global
// packed in MFMA fragment order (prep kernel) and are re-loaded per iteration
// (L1/L2-hot, coalesced) -- never register-resident (R3's spill disaster).
// Projections use K=32 MFMA; energy/PV/FC keep the verified K=16 same-lane
// accumulator-reuse chains. Precision: X split hi/lo, q/k accumulators split
// for energy (3 pairings); W hi-only; softmax/GN/residual fp32.

typedef float  f4    __attribute__((ext_vector_type(4)));
typedef float  f32x4 __attribute__((ext_vector_type(4)));
typedef short  s16x4 __attribute__((ext_vector_type(4)));
typedef short  s16x8 __attribute__((ext_vector_type(8)));
typedef unsigned short u16;
typedef __bf16 bf16;

#define MFMA16(a,b,c) __builtin_amdgcn_mfma_f32_16x16x16bf16_1k((a),(b),(c),0,0,0)
#define MFMA32(a,b,c) __builtin_amdgcn_mfma_f32_16x16x32_bf16((a),(b),(c),0,0,0)

// slot0=Wq(K32) slot1=Wk(K32) slot2=Wv(K32) slot3=Wfc(K16); 4 x 8KB
__device__ __align__(16) u16 g_wpack[4 * 4096];

__device__ __forceinline__ u16 bfbits(float x) {
  return __builtin_bit_cast(u16, (bf16)x);
}

// K32 frag: pack[t=a*2+b][l][j0..7] = W[16a + (l&15)][32b + 8*(l>>4) + j]
// K16 frag: pack[t=a*4+b][l][j0..3] = W[16a + (l&15)][16b + 4*(l>>4) + j]
__global__ void prep_w(const float* __restrict__ Wq, const float* __restrict__ Wk,
                       const float* __restrict__ Wv, const float* __restrict__ Wfc)
{
  const int t = threadIdx.x;  // 256 threads
  const float* Wm[3] = {Wq, Wk, Wv};
#pragma unroll
  for (int s = 0; s < 3; ++s) {
    const float* W = Wm[s];
    for (int e = t; e < 512; e += 256) {   // e = tile*64 + lane
      const int tile = e >> 6, l = e & 63;
      const int row = 16 * (tile >> 1) + (l & 15);
      const int col = 32 * (tile & 1) + 8 * (l >> 4);
#pragma unroll
      for (int j = 0; j < 8; ++j)
        g_wpack[s * 4096 + e * 8 + j] = bfbits(W[row * 64 + col + j]);
    }
  }
  for (int e = t; e < 1024; e += 256) {
    const int tile = e >> 6, l = e & 63;
    const int row = 16 * (tile >> 2) + (l & 15);
    const int col = 16 * (tile & 3) + 4 * (l >> 4);
#pragma unroll
    for (int j = 0; j < 4; ++j)
      g_wpack[3 * 4096 + e * 4 + j] = bfbits(Wfc[row * 64 + col + j]);
  }
}

__global__ void __launch_bounds__(256, 3)
cvbt4(const float* __restrict__ qx, const float* __restrict__ rx,
      const float* __restrict__ gw, const float* __restrict__ gb,
      float* __restrict__ out)
{
  // strip layout: element (c, r, w) at dword c*68 + r*16 + 4*((w>>2)^r^((c>>3)&3)) + (w&3)
  __shared__ __align__(16) float sXq[64 * 68];   // 17408 B
  __shared__ __align__(16) float sXr[64 * 68];   // 17408 B (reused for output)
  __shared__ u16   sP[4 * 320];                  //  2560 B (per-wave attn)
  __shared__ float sGn[128];                     //   512 B

  const int tid  = threadIdx.x;
  const int wv   = tid >> 6;     // wave = block within strip
  const int lane = tid & 63;
  const int n  = lane & 15;      // pixel index within block
  const int g  = lane >> 4;      // 4-row group
  const int rp = n >> 2;         // pixel row
  const int wl = n & 3;          // pixel col (low 2 bits)

  if (tid < 128) sGn[tid] = (tid < 64) ? gw[tid] : gb[tid - 64];

  const int bid = blockIdx.x;
  const int wid = (bid & 7) * 256 + (bid >> 3);  // XCD-contiguous (2048 = 8*256)

  const u16* wp = g_wpack;
  u16* sPw = &sP[wv * 320];
  const f32x4 zero = {0.f, 0.f, 0.f, 0.f};

#pragma unroll 1
  for (int si = wid; si < 8192; si += 2048) {
    asm volatile("" : "+s"(wp));   // anti-LICM: weight loads stay in-loop
    const uint32_t b  = (uint32_t)si >> 10;
    const uint32_t hb = ((uint32_t)si >> 4) & 63;
    const uint32_t ws = (uint32_t)si & 15;
    const uint32_t sbase = b * 4194304u + hb * 1024u + ws * 16u;

    __syncthreads();  // previous coop-store done before overwriting LDS
    // ---- cooperative coalesced load: 4KB (64 dense 64B lines) per instr ----
#pragma unroll
    for (int it = 0; it < 4; ++it) {
      const int i = it * 256 + tid;
      const int c = i >> 4, r = (i >> 2) & 3, w4 = i & 3;
      const uint32_t ga = sbase + (uint32_t)c * 65536u + (uint32_t)r * 256u + (uint32_t)w4 * 4u;
      const int dw = c * 68 + r * 16 + 4 * (w4 ^ r ^ ((c >> 3) & 3));
      *(f4*)&sXq[dw] = *(const f4*)(qx + ga);
      *(f4*)&sXr[dw] = *(const f4*)(rx + ga);
    }
    __syncthreads();

    // ---- X frags (K32 layout, hi/lo), wave reads only its own columns ----
    s16x8 fqh[2], fql[2], frh[2], frl[2];
#pragma unroll
    for (int kt = 0; kt < 2; ++kt)
#pragma unroll
      for (int j = 0; j < 8; ++j) {
        const int c = 32 * kt + 8 * g + j;      // (c>>3)&3 == g here
        const int dw = c * 68 + rp * 16 + 4 * (wv ^ rp ^ g) + wl;
        float x1 = sXq[dw];
        bf16 h1 = (bf16)x1;
        fqh[kt][j] = (short)__builtin_bit_cast(u16, h1);
        fql[kt][j] = (short)bfbits(x1 - (float)h1);
        float x2 = sXr[dw];
        bf16 h2 = (bf16)x2;
        frh[kt][j] = (short)__builtin_bit_cast(u16, h2);
        frl[kt][j] = (short)bfbits(x2 - (float)h2);
      }

    // ---- q = Wq*Xq, k = Wk*Xr (K32, Wh*(Xh+Xl)) ----
    f32x4 aq[4], ak[4];
#pragma unroll
    for (int mt = 0; mt < 4; ++mt) { aq[mt] = zero; ak[mt] = zero; }
#pragma unroll
    for (int mt = 0; mt < 4; ++mt)
#pragma unroll
      for (int kt = 0; kt < 2; ++kt) {
        s16x8 w1 = *(const s16x8*)(wp + 0 * 4096 + ((mt * 2 + kt) * 64 + lane) * 8);
        aq[mt] = MFMA32(w1, fqh[kt], aq[mt]);
        aq[mt] = MFMA32(w1, fql[kt], aq[mt]);
        s16x8 w2 = *(const s16x8*)(wp + 1 * 4096 + ((mt * 2 + kt) * 64 + lane) * 8);
        ak[mt] = MFMA32(w2, frh[kt], ak[mt]);
        ak[mt] = MFMA32(w2, frl[kt], ak[mt]);
      }
    // aq[mt][r] = q[16mt+4g+r][n]; ak likewise.

    // ---- v tiles (K32): av[nt][r] = v[16nt+n][4g+r] ----
    f32x4 av[4];
#pragma unroll
    for (int nt = 0; nt < 4; ++nt) {
      av[nt] = zero;
#pragma unroll
      for (int kt = 0; kt < 2; ++kt) {
        s16x8 w3 = *(const s16x8*)(wp + 2 * 4096 + ((nt * 2 + kt) * 64 + lane) * 8);
        av[nt] = MFMA32(frh[kt], w3, av[nt]);
      }
    }

    // ---- split q,k accumulators (energy frags, same lane, K16 chains) ----
    s16x4 qh[4], ql[4], kh[4], kl[4];
#pragma unroll
    for (int kt = 0; kt < 4; ++kt)
#pragma unroll
      for (int r = 0; r < 4; ++r) {
        bf16 h = (bf16)aq[kt][r];
        qh[kt][r] = (short)__builtin_bit_cast(u16, h);
        ql[kt][r] = (short)bfbits(aq[kt][r] - (float)h);
        bf16 h2 = (bf16)ak[kt][r];
        kh[kt][r] = (short)__builtin_bit_cast(u16, h2);
        kl[kt][r] = (short)bfbits(ak[kt][r] - (float)h2);
      }

    // ---- energy = q^T k : e[r] = E[qpix=4g+r][refpix=n] ----
    f32x4 e = zero;
#pragma unroll
    for (int kt = 0; kt < 4; ++kt) {
      e = MFMA16(qh[kt], kh[kt], e);
      e = MFMA16(qh[kt], kl[kt], e);
      e = MFMA16(ql[kt], kh[kt], e);
    }

    // ---- softmax over refpix ----
#pragma unroll
    for (int r = 0; r < 4; ++r) {
      float x = e[r];
      float m = x;
      m = fmaxf(m, __shfl_xor(m, 1));
      m = fmaxf(m, __shfl_xor(m, 2));
      m = fmaxf(m, __shfl_xor(m, 4));
      m = fmaxf(m, __shfl_xor(m, 8));
      float p = __expf(x - m);
      float s = p;
      s += __shfl_xor(s, 1);
      s += __shfl_xor(s, 2);
      s += __shfl_xor(s, 4);
      s += __shfl_xor(s, 8);
      sPw[(4 * g + r) * 20 + n] = bfbits(p * __builtin_amdgcn_rcpf(s));
    }

    // ---- O tiles: A = v (same lane), B = attn^T (wave-private LDS) ----
    s16x4 pa = *(const s16x4*)&sPw[n * 20 + 4 * g];  // attn[n][4g+j]
    f32x4 ao[4];
#pragma unroll
    for (int mt = 0; mt < 4; ++mt) {
      s16x4 vb;
#pragma unroll
      for (int j = 0; j < 4; ++j) vb[j] = (short)bfbits(av[mt][j]);
      ao[mt] = MFMA16(vb, pa, zero);   // ao[mt][r] = O[16mt+4g+r][n]
    }

    // ---- x = Wfc * O (K16; B-frag = ao as bf16, same lane) ----
    s16x4 ob[4];
#pragma unroll
    for (int kt = 0; kt < 4; ++kt)
#pragma unroll
      for (int j = 0; j < 4; ++j) ob[kt][j] = (short)bfbits(ao[kt][j]);
    f32x4 xa[4];
#pragma unroll
    for (int mt = 0; mt < 4; ++mt) {
      xa[mt] = zero;
#pragma unroll
      for (int kt = 0; kt < 4; ++kt) {
        s16x4 w = *(const s16x4*)(wp + 3 * 4096 + ((mt * 4 + kt) * 64 + lane) * 4);
        xa[mt] = MFMA16(w, ob[kt], xa[mt]);
      }
    }

    // ---- GroupNorm over 64x16 (fp32) ----
    float s1 = 0.f, s2 = 0.f;
#pragma unroll
    for (int mt = 0; mt < 4; ++mt)
#pragma unroll
      for (int r = 0; r < 4; ++r) {
        float v = xa[mt][r];
        s1 += v; s2 += v * v;
      }
#pragma unroll
    for (int mask = 1; mask < 64; mask <<= 1) {
      s1 += __shfl_xor(s1, mask);
      s2 += __shfl_xor(s2, mask);
    }
    const float mean = s1 * (1.f / 1024.f);
    const float var  = s2 * (1.f / 1024.f) - mean * mean;
    const float rstd = rsqrtf(var + 1e-5f);

    // ---- affine + exact fp32 residual -> out staging (own columns of sXr) ----
#pragma unroll
    for (int mt = 0; mt < 4; ++mt)
#pragma unroll
      for (int r = 0; r < 4; ++r) {
        const int row = 16 * mt + 4 * g + r;
        const int dw = row * 68 + rp * 16 + 4 * (wv ^ rp ^ ((row >> 3) & 3)) + wl;
        sXr[dw] = (xa[mt][r] - mean) * rstd * sGn[row] + sGn[64 + row] + sXq[dw];
      }
    __syncthreads();

    // ---- cooperative coalesced store ----
#pragma unroll
    for (int it = 0; it < 4; ++it) {
      const int i = it * 256 + tid;
      const int c = i >> 4, r = (i >> 2) & 3, w4 = i & 3;
      const uint32_t ga = sbase + (uint32_t)c * 65536u + (uint32_t)r * 256u + (uint32_t)w4 * 4u;
      const int dw = c * 68 + r * 16 + 4 * (w4 ^ r ^ ((c >> 3) & 3));
      *(f4*)(out + ga) = *(const f4*)&sXr[dw];
    }
  }
}

extern "C" void kernel_launch(void* const* d_in, const int* in_sizes, int n_in,
                              void* d_out, int out_size, void* d_ws, size_t ws_size,
                              hipStream_t stream) {
  const float* qx  = (const float*)d_in[0];
  const float* rx  = (const float*)d_in[1];
  const float* Wq  = (const float*)d_in[2];
  const float* Wk  = (const float*)d_in[3];
  const float* Wv  = (const float*)d_in[4];
  const float* Wfc = (const float*)d_in[5];
  const float* gw  = (const float*)d_in[6];
  const float* gb  = (const float*)d_in[7];
  float* out = (float*)d_out;

  prep_w<<<dim3(1), dim3(256), 0, stream>>>(Wq, Wk, Wv, Wfc);
  // 2048 WGs (8 WG/CU over time), 4 strips each; 8192 strips total
  cvbt4<<<dim3(2048), dim3(256), 0, stream>>>(qx, rx, gw, gb, out);
}

// Round 5
// 173.191 us; speedup vs baseline: 2.6425x; 1.2338x over previous
//
#include <hip/hip_runtime.h>
#include <cstdint>

// CrossViewBlockTransformer on MI355X (gfx950), round 5.
// R4 structure (WG=256 = 4 waves on a strip of 4 adjacent 4x4 blocks,
// coalesced strip loads/stores via XOR-swizzled LDS, frag-ordered weights in
// a __device__ global, same-lane MFMA accumulator-reuse chains) plus:
//   - T14 async-STAGE register pipeline: next strip's global loads issue
//     right after the ds_write barrier and complete under current compute.
//   - launch_bounds(256,4): 16 waves/CU target (LDS allows 4 WG/CU).
//   - non-temporal output stores (keep L2/L3 for inputs + weights).
// Arithmetic sequence is bit-identical to R4 (absmax 0.1484375).

typedef float  f4    __attribute__((ext_vector_type(4)));
typedef float  f32x4 __attribute__((ext_vector_type(4)));
typedef short  s16x4 __attribute__((ext_vector_type(4)));
typedef short  s16x8 __attribute__((ext_vector_type(8)));
typedef unsigned short u16;
typedef __bf16 bf16;

#define MFMA16(a,b,c) __builtin_amdgcn_mfma_f32_16x16x16bf16_1k((a),(b),(c),0,0,0)
#define MFMA32(a,b,c) __builtin_amdgcn_mfma_f32_16x16x32_bf16((a),(b),(c),0,0,0)

// slot0=Wq(K32) slot1=Wk(K32) slot2=Wv(K32) slot3=Wfc(K16); 4 x 8KB
__device__ __align__(16) u16 g_wpack[4 * 4096];

__device__ __forceinline__ u16 bfbits(float x) {
  return __builtin_bit_cast(u16, (bf16)x);
}

// K32 frag: pack[t=a*2+b][l][j0..7] = W[16a + (l&15)][32b + 8*(l>>4) + j]
// K16 frag: pack[t=a*4+b][l][j0..3] = W[16a + (l&15)][16b + 4*(l>>4) + j]
__global__ void prep_w(const float* __restrict__ Wq, const float* __restrict__ Wk,
                       const float* __restrict__ Wv, const float* __restrict__ Wfc)
{
  const int t = threadIdx.x;  // 256 threads
  const float* Wm[3] = {Wq, Wk, Wv};
#pragma unroll
  for (int s = 0; s < 3; ++s) {
    const float* W = Wm[s];
    for (int e = t; e < 512; e += 256) {   // e = tile*64 + lane
      const int tile = e >> 6, l = e & 63;
      const int row = 16 * (tile >> 1) + (l & 15);
      const int col = 32 * (tile & 1) + 8 * (l >> 4);
#pragma unroll
      for (int j = 0; j < 8; ++j)
        g_wpack[s * 4096 + e * 8 + j] = bfbits(W[row * 64 + col + j]);
    }
  }
  for (int e = t; e < 1024; e += 256) {
    const int tile = e >> 6, l = e & 63;
    const int row = 16 * (tile >> 2) + (l & 15);
    const int col = 16 * (tile & 3) + 4 * (l >> 4);
#pragma unroll
    for (int j = 0; j < 4; ++j)
      g_wpack[3 * 4096 + e * 4 + j] = bfbits(Wfc[row * 64 + col + j]);
  }
}

__global__ void __launch_bounds__(256, 4)
cvbt5(const float* __restrict__ qx, const float* __restrict__ rx,
      const float* __restrict__ gw, const float* __restrict__ gb,
      float* __restrict__ out)
{
  // strip layout: element (c, r, w) at dword c*68 + r*16 + 4*((w>>2)^r^((c>>3)&3)) + (w&3)
  __shared__ __align__(16) float sXq[64 * 68];   // 17408 B
  __shared__ __align__(16) float sXr[64 * 68];   // 17408 B (reused for output)
  __shared__ u16   sP[4 * 320];                  //  2560 B (per-wave attn)
  __shared__ float sGn[128];                     //   512 B

  const int tid  = threadIdx.x;
  const int wv   = tid >> 6;     // wave = block within strip
  const int lane = tid & 63;
  const int n  = lane & 15;      // pixel index within block
  const int g  = lane >> 4;      // 4-row group
  const int rp = n >> 2;         // pixel row
  const int wl = n & 3;          // pixel col (low 2 bits)

  if (tid < 128) sGn[tid] = (tid < 64) ? gw[tid] : gb[tid - 64];

  // coop-transfer addressing (iteration-invariant)
  int      dwIdx[4];
  uint32_t gofs[4];
#pragma unroll
  for (int it = 0; it < 4; ++it) {
    const int i = it * 256 + tid;
    const int c = i >> 4, r = (i >> 2) & 3, w4 = i & 3;
    dwIdx[it] = c * 68 + r * 16 + 4 * (w4 ^ r ^ ((c >> 3) & 3));
    gofs[it]  = (uint32_t)c * 65536u + (uint32_t)r * 256u + (uint32_t)w4 * 4u;
  }

  const int bid = blockIdx.x;
  const int wid = (bid & 7) * 256 + (bid >> 3);  // XCD-contiguous (2048 = 8*256)

  const u16* wp = g_wpack;
  u16* sPw = &sP[wv * 320];
  const f32x4 zero = {0.f, 0.f, 0.f, 0.f};

  // ---- prologue: issue loads for first strip ----
  auto sbase = [](int si) -> uint32_t {
    const uint32_t b  = (uint32_t)si >> 10;
    const uint32_t hb = ((uint32_t)si >> 4) & 63;
    const uint32_t ws = (uint32_t)si & 15;
    return b * 4194304u + hb * 1024u + ws * 16u;
  };
  uint32_t sb = sbase(wid);
  f4 pq[4], pr[4];
#pragma unroll
  for (int it = 0; it < 4; ++it) {
    pq[it] = *(const f4*)(qx + sb + gofs[it]);
    pr[it] = *(const f4*)(rx + sb + gofs[it]);
  }

#pragma unroll 1
  for (int si = wid; si < 8192; si += 2048) {
    asm volatile("" : "+s"(wp));   // anti-LICM: weight loads stay in-loop
    const int nexts = (si + 2048 < 8192) ? si + 2048 : si;
    const uint32_t nsb = sbase(nexts);

    __syncthreads();  // previous coop-store done before overwriting LDS
    // ---- write current strip (prefetched last iter) to LDS ----
#pragma unroll
    for (int it = 0; it < 4; ++it) {
      *(f4*)&sXq[dwIdx[it]] = pq[it];
      *(f4*)&sXr[dwIdx[it]] = pr[it];
    }
    __syncthreads();

    // ---- issue next strip's global loads (complete under compute) ----
    f4 nq[4], nr[4];
#pragma unroll
    for (int it = 0; it < 4; ++it) {
      nq[it] = *(const f4*)(qx + nsb + gofs[it]);
      nr[it] = *(const f4*)(rx + nsb + gofs[it]);
    }

    // ---- X frags (K32 layout, hi/lo), wave reads only its own columns ----
    s16x8 fqh[2], fql[2], frh[2], frl[2];
#pragma unroll
    for (int kt = 0; kt < 2; ++kt)
#pragma unroll
      for (int j = 0; j < 8; ++j) {
        const int c = 32 * kt + 8 * g + j;      // (c>>3)&3 == g here
        const int dw = c * 68 + rp * 16 + 4 * (wv ^ rp ^ g) + wl;
        float x1 = sXq[dw];
        bf16 h1 = (bf16)x1;
        fqh[kt][j] = (short)__builtin_bit_cast(u16, h1);
        fql[kt][j] = (short)bfbits(x1 - (float)h1);
        float x2 = sXr[dw];
        bf16 h2 = (bf16)x2;
        frh[kt][j] = (short)__builtin_bit_cast(u16, h2);
        frl[kt][j] = (short)bfbits(x2 - (float)h2);
      }

    // ---- q = Wq*Xq, k = Wk*Xr (K32, Wh*(Xh+Xl)) ----
    f32x4 aq[4], ak[4];
#pragma unroll
    for (int mt = 0; mt < 4; ++mt) { aq[mt] = zero; ak[mt] = zero; }
#pragma unroll
    for (int mt = 0; mt < 4; ++mt)
#pragma unroll
      for (int kt = 0; kt < 2; ++kt) {
        s16x8 w1 = *(const s16x8*)(wp + 0 * 4096 + ((mt * 2 + kt) * 64 + lane) * 8);
        aq[mt] = MFMA32(w1, fqh[kt], aq[mt]);
        aq[mt] = MFMA32(w1, fql[kt], aq[mt]);
        s16x8 w2 = *(const s16x8*)(wp + 1 * 4096 + ((mt * 2 + kt) * 64 + lane) * 8);
        ak[mt] = MFMA32(w2, frh[kt], ak[mt]);
        ak[mt] = MFMA32(w2, frl[kt], ak[mt]);
      }
    // aq[mt][r] = q[16mt+4g+r][n]; ak likewise.

    // ---- v tiles (K32): av[nt][r] = v[16nt+n][4g+r] ----
    f32x4 av[4];
#pragma unroll
    for (int nt = 0; nt < 4; ++nt) {
      av[nt] = zero;
#pragma unroll
      for (int kt = 0; kt < 2; ++kt) {
        s16x8 w3 = *(const s16x8*)(wp + 2 * 4096 + ((nt * 2 + kt) * 64 + lane) * 8);
        av[nt] = MFMA32(frh[kt], w3, av[nt]);
      }
    }

    // ---- split q,k accumulators (energy frags, same lane, K16 chains) ----
    s16x4 qh[4], ql[4], kh[4], kl[4];
#pragma unroll
    for (int kt = 0; kt < 4; ++kt)
#pragma unroll
      for (int r = 0; r < 4; ++r) {
        bf16 h = (bf16)aq[kt][r];
        qh[kt][r] = (short)__builtin_bit_cast(u16, h);
        ql[kt][r] = (short)bfbits(aq[kt][r] - (float)h);
        bf16 h2 = (bf16)ak[kt][r];
        kh[kt][r] = (short)__builtin_bit_cast(u16, h2);
        kl[kt][r] = (short)bfbits(ak[kt][r] - (float)h2);
      }

    // ---- energy = q^T k : e[r] = E[qpix=4g+r][refpix=n] ----
    f32x4 e = zero;
#pragma unroll
    for (int kt = 0; kt < 4; ++kt) {
      e = MFMA16(qh[kt], kh[kt], e);
      e = MFMA16(qh[kt], kl[kt], e);
      e = MFMA16(ql[kt], kh[kt], e);
    }

    // ---- softmax over refpix ----
#pragma unroll
    for (int r = 0; r < 4; ++r) {
      float x = e[r];
      float m = x;
      m = fmaxf(m, __shfl_xor(m, 1));
      m = fmaxf(m, __shfl_xor(m, 2));
      m = fmaxf(m, __shfl_xor(m, 4));
      m = fmaxf(m, __shfl_xor(m, 8));
      float p = __expf(x - m);
      float s = p;
      s += __shfl_xor(s, 1);
      s += __shfl_xor(s, 2);
      s += __shfl_xor(s, 4);
      s += __shfl_xor(s, 8);
      sPw[(4 * g + r) * 20 + n] = bfbits(p * __builtin_amdgcn_rcpf(s));
    }

    // ---- O tiles: A = v (same lane), B = attn^T (wave-private LDS) ----
    s16x4 pa = *(const s16x4*)&sPw[n * 20 + 4 * g];  // attn[n][4g+j]
    f32x4 ao[4];
#pragma unroll
    for (int mt = 0; mt < 4; ++mt) {
      s16x4 vb;
#pragma unroll
      for (int j = 0; j < 4; ++j) vb[j] = (short)bfbits(av[mt][j]);
      ao[mt] = MFMA16(vb, pa, zero);   // ao[mt][r] = O[16mt+4g+r][n]
    }

    // ---- x = Wfc * O (K16; B-frag = ao as bf16, same lane) ----
    s16x4 ob[4];
#pragma unroll
    for (int kt = 0; kt < 4; ++kt)
#pragma unroll
      for (int j = 0; j < 4; ++j) ob[kt][j] = (short)bfbits(ao[kt][j]);
    f32x4 xa[4];
#pragma unroll
    for (int mt = 0; mt < 4; ++mt) {
      xa[mt] = zero;
#pragma unroll
      for (int kt = 0; kt < 4; ++kt) {
        s16x4 w = *(const s16x4*)(wp + 3 * 4096 + ((mt * 4 + kt) * 64 + lane) * 4);
        xa[mt] = MFMA16(w, ob[kt], xa[mt]);
      }
    }

    // ---- GroupNorm over 64x16 (fp32) ----
    float s1 = 0.f, s2 = 0.f;
#pragma unroll
    for (int mt = 0; mt < 4; ++mt)
#pragma unroll
      for (int r = 0; r < 4; ++r) {
        float v = xa[mt][r];
        s1 += v; s2 += v * v;
      }
#pragma unroll
    for (int mask = 1; mask < 64; mask <<= 1) {
      s1 += __shfl_xor(s1, mask);
      s2 += __shfl_xor(s2, mask);
    }
    const float mean = s1 * (1.f / 1024.f);
    const float var  = s2 * (1.f / 1024.f) - mean * mean;
    const float rstd = rsqrtf(var + 1e-5f);

    // ---- affine + exact fp32 residual -> out staging (own columns of sXr) ----
#pragma unroll
    for (int mt = 0; mt < 4; ++mt)
#pragma unroll
      for (int r = 0; r < 4; ++r) {
        const int row = 16 * mt + 4 * g + r;
        const int dw = row * 68 + rp * 16 + 4 * (wv ^ rp ^ ((row >> 3) & 3)) + wl;
        sXr[dw] = (xa[mt][r] - mean) * rstd * sGn[row] + sGn[64 + row] + sXq[dw];
      }
    __syncthreads();

    // ---- cooperative coalesced store (non-temporal) ----
#pragma unroll
    for (int it = 0; it < 4; ++it) {
      f4 o = *(const f4*)&sXr[dwIdx[it]];
      __builtin_nontemporal_store(o, (f4*)(out + sb + gofs[it]));
    }

    // ---- rotate prefetch registers ----
#pragma unroll
    for (int it = 0; it < 4; ++it) { pq[it] = nq[it]; pr[it] = nr[it]; }
    sb = nsb;
  }
}

extern "C" void kernel_launch(void* const* d_in, const int* in_sizes, int n_in,
                              void* d_out, int out_size, void* d_ws, size_t ws_size,
                              hipStream_t stream) {
  const float* qx  = (const float*)d_in[0];
  const float* rx  = (const float*)d_in[1];
  const float* Wq  = (const float*)d_in[2];
  const float* Wk  = (const float*)d_in[3];
  const float* Wv  = (const float*)d_in[4];
  const float* Wfc = (const float*)d_in[5];
  const float* gw  = (const float*)d_in[6];
  const float* gb  = (const float*)d_in[7];
  float* out = (float*)d_out;

  prep_w<<<dim3(1), dim3(256), 0, stream>>>(Wq, Wk, Wv, Wfc);
  // 2048 WGs (4 strips each; 8192 strips total), multiple of 8 for swizzle
  cvbt5<<<dim3(2048), dim3(256), 0, stream>>>(qx, rx, gw, gb, out);
}

// Round 6
// 109.828 us; speedup vs baseline: 4.1671x; 1.5769x over previous
//
#include <hip/hip_runtime.h>
#include <cstdint>

// CrossViewBlockTransformer on MI355X (gfx950), round 6.
// WG = 256 (4 waves) on a strip of 4 adjacent 4x4 blocks.
// - Staging via __builtin_amdgcn_global_load_lds (width 16): linear LDS dest,
//   XOR-swizzle pre-applied to the per-lane GLOBAL source address (rule #21).
// - Ping-pong Xq regions: staging(t) reuses the region Xq(t) occupied; loads
//   for Xq(t+1) land in the other. Xr single region (dead after extraction).
// - Raw s_barrier + hand-counted s_waitcnt: loop-top vmcnt(4) drains exactly
//   the 8 strip loads (stores are the 4 youngest, never waited).
// - All weight fragments hoisted to registers outside the loop (128 VGPR);
//   in-loop vmem = 8 load_lds + 4 stores only. launch_bounds(256,2), cap 256.
// Arithmetic identical to R4/R5 (absmax 0.1484375).

typedef float  f4    __attribute__((ext_vector_type(4)));
typedef float  f32x4 __attribute__((ext_vector_type(4)));
typedef short  s16x4 __attribute__((ext_vector_type(4)));
typedef short  s16x8 __attribute__((ext_vector_type(8)));
typedef unsigned short u16;
typedef __bf16 bf16;

#define MFMA16(a,b,c) __builtin_amdgcn_mfma_f32_16x16x16bf16_1k((a),(b),(c),0,0,0)
#define MFMA32(a,b,c) __builtin_amdgcn_mfma_f32_16x16x32_bf16((a),(b),(c),0,0,0)

// slot0=Wq(K32) slot1=Wk(K32) slot2=Wv(K32) slot3=Wfc(K16); 4 x 8KB
__device__ __align__(16) u16 g_wpack[4 * 4096];

__device__ __forceinline__ u16 bfbits(float x) {
  return __builtin_bit_cast(u16, (bf16)x);
}

__device__ __forceinline__ void gload_lds16(const float* g, float* l) {
  __builtin_amdgcn_global_load_lds(
      (const __attribute__((address_space(1))) void*)g,
      (__attribute__((address_space(3))) void*)l, 16, 0, 0);
}

// K32 frag: pack[t=a*2+b][l][j0..7] = W[16a + (l&15)][32b + 8*(l>>4) + j]
// K16 frag: pack[t=a*4+b][l][j0..3] = W[16a + (l&15)][16b + 4*(l>>4) + j]
__global__ void prep_w(const float* __restrict__ Wq, const float* __restrict__ Wk,
                       const float* __restrict__ Wv, const float* __restrict__ Wfc)
{
  const int t = threadIdx.x;  // 256 threads
  const float* Wm[3] = {Wq, Wk, Wv};
#pragma unroll
  for (int s = 0; s < 3; ++s) {
    const float* W = Wm[s];
    for (int e = t; e < 512; e += 256) {
      const int tile = e >> 6, l = e & 63;
      const int row = 16 * (tile >> 1) + (l & 15);
      const int col = 32 * (tile & 1) + 8 * (l >> 4);
#pragma unroll
      for (int j = 0; j < 8; ++j)
        g_wpack[s * 4096 + e * 8 + j] = bfbits(W[row * 64 + col + j]);
    }
  }
  for (int e = t; e < 1024; e += 256) {
    const int tile = e >> 6, l = e & 63;
    const int row = 16 * (tile >> 2) + (l & 15);
    const int col = 16 * (tile & 3) + 4 * (l >> 4);
#pragma unroll
    for (int j = 0; j < 4; ++j)
      g_wpack[3 * 4096 + e * 4 + j] = bfbits(Wfc[row * 64 + col + j]);
  }
}

__global__ void __launch_bounds__(256, 2)
cvbt6(const float* __restrict__ qx, const float* __restrict__ rx,
      const float* __restrict__ gw, const float* __restrict__ gb,
      float* __restrict__ out)
{
  // linear-slot layout: element (c, r, w4group, wl) at float index
  //   c*64 + r*16 + 4*(w4 ^ r ^ ((c>>3)&3)) + wl      (swizzle in source addr)
  __shared__ __align__(16) float sQ[2][4096];  // Xq ping-pong / out staging (2x16KB)
  __shared__ __align__(16) float sR[4096];     // Xr (16KB)
  __shared__ u16   sP[4 * 320];                // per-wave attn (2.5KB)
  __shared__ float sGn[128];                   // gamma|beta (0.5KB)

  const int tid  = threadIdx.x;
  const int wv   = tid >> 6, lane = tid & 63;
  const int n = lane & 15, g = lane >> 4, rp = n >> 2, wl = n & 3;

  if (tid < 128) sGn[tid] = (tid < 64) ? gw[tid] : gb[tid - 64];

  // ---- hoisted weight fragments (128 VGPR, live across the loop) ----
  s16x8 Wq8[4][2], Wk8[4][2], Wv8[4][2];
  s16x4 Wf4[4][4];
#pragma unroll
  for (int a = 0; a < 4; ++a) {
#pragma unroll
    for (int c2 = 0; c2 < 2; ++c2) {
      Wq8[a][c2] = *(const s16x8*)(g_wpack + 0 * 4096 + ((a * 2 + c2) * 64 + lane) * 8);
      Wk8[a][c2] = *(const s16x8*)(g_wpack + 1 * 4096 + ((a * 2 + c2) * 64 + lane) * 8);
      Wv8[a][c2] = *(const s16x8*)(g_wpack + 2 * 4096 + ((a * 2 + c2) * 64 + lane) * 8);
    }
#pragma unroll
    for (int c4 = 0; c4 < 4; ++c4)
      Wf4[a][c4] = *(const s16x4*)(g_wpack + 3 * 4096 + ((a * 4 + c4) * 64 + lane) * 4);
  }

  // ---- chunk addressing: chunk j = s*4 + wv covers channels 4j..4j+3 ----
  uint32_t goff[4]; int lbase[4];
#pragma unroll
  for (int s = 0; s < 4; ++s) {
    const int j = s * 4 + wv;
    const int c = 4 * j + (lane >> 4);
    const int r = (lane >> 2) & 3, y = lane & 3;
    const int w4 = y ^ r ^ ((c >> 3) & 3);
    goff[s]  = (uint32_t)c * 65536u + (uint32_t)r * 256u + (uint32_t)w4 * 4u;
    lbase[s] = j * 256;
  }

  const int bid = blockIdx.x;
  const int wid = (bid & 7) * 64 + (bid >> 3);  // XCD-contiguous (512 = 8*64)
  const int si0 = wid * 16;

  auto sbase = [](int si) -> uint32_t {
    return ((uint32_t)si >> 10) * 4194304u + (((uint32_t)si >> 4) & 63) * 1024u +
           ((uint32_t)si & 15) * 16u;
  };

  // ---- prologue: strip 0 loads, full drain ----
  uint32_t sb = sbase(si0);
#pragma unroll
  for (int s = 0; s < 4; ++s) {
    gload_lds16(qx + sb + goff[s], &sQ[0][lbase[s]]);
    gload_lds16(rx + sb + goff[s], &sR[lbase[s]]);
  }
  asm volatile("s_waitcnt vmcnt(0) lgkmcnt(0)" ::: "memory");

  const f32x4 zero = {0.f, 0.f, 0.f, 0.f};
  u16* sPw = &sP[wv * 320];
  int pp = 0;

#pragma unroll 1
  for (int t = 0; t < 16; ++t) {
    const uint32_t nsb = sbase(si0 + (t < 15 ? t + 1 : t));

    // B1: strip-t loads complete everywhere (stores are the <=4 youngest)
    asm volatile("s_waitcnt vmcnt(4)" ::: "memory");
    __builtin_amdgcn_s_barrier();
    __builtin_amdgcn_sched_barrier(0);

    // ---- extract Xr frags (hi/lo); x(c)=g for c=32kt+8g+j ----
    s16x8 frh[2], frl[2];
#pragma unroll
    for (int kt = 0; kt < 2; ++kt)
#pragma unroll
      for (int j = 0; j < 8; ++j) {
        const int addr = (32 * kt + 8 * g + j) * 64 + rp * 16 + 4 * (wv ^ rp ^ g) + wl;
        float x2 = sR[addr];
        bf16 h = (bf16)x2;
        frh[kt][j] = (short)__builtin_bit_cast(u16, h);
        frl[kt][j] = (short)bfbits(x2 - (float)h);
      }

    // B2: all waves done reading Xr -> safe to overwrite
    asm volatile("s_waitcnt lgkmcnt(0)" ::: "memory");
    __builtin_amdgcn_s_barrier();
    __builtin_amdgcn_sched_barrier(0);

    // ---- issue strip t+1 loads (hide under the whole iteration) ----
#pragma unroll
    for (int s = 0; s < 4; ++s) {
      gload_lds16(qx + nsb + goff[s], &sQ[pp ^ 1][lbase[s]]);
      gload_lds16(rx + nsb + goff[s], &sR[lbase[s]]);
    }
    __builtin_amdgcn_sched_barrier(0);

    // ---- k = Wk*Xr, v tiles (K32) ----
    f32x4 ak[4], av[4];
#pragma unroll
    for (int mt = 0; mt < 4; ++mt) { ak[mt] = zero; av[mt] = zero; }
#pragma unroll
    for (int mt = 0; mt < 4; ++mt)
#pragma unroll
      for (int kt = 0; kt < 2; ++kt) {
        ak[mt] = MFMA32(Wk8[mt][kt], frh[kt], ak[mt]);
        ak[mt] = MFMA32(Wk8[mt][kt], frl[kt], ak[mt]);
      }
#pragma unroll
    for (int nt = 0; nt < 4; ++nt)
#pragma unroll
      for (int kt = 0; kt < 2; ++kt)
        av[nt] = MFMA32(frh[kt], Wv8[nt][kt], av[nt]);

    // ---- extract Xq frags (sQ[pp] is wave-column private; loads went to pp^1)
    s16x8 fqh[2], fql[2];
#pragma unroll
    for (int kt = 0; kt < 2; ++kt)
#pragma unroll
      for (int j = 0; j < 8; ++j) {
        const int addr = (32 * kt + 8 * g + j) * 64 + rp * 16 + 4 * (wv ^ rp ^ g) + wl;
        float x1 = sQ[pp][addr];
        bf16 h = (bf16)x1;
        fqh[kt][j] = (short)__builtin_bit_cast(u16, h);
        fql[kt][j] = (short)bfbits(x1 - (float)h);
      }
    f32x4 aq[4];
#pragma unroll
    for (int mt = 0; mt < 4; ++mt) {
      aq[mt] = zero;
#pragma unroll
      for (int kt = 0; kt < 2; ++kt) {
        aq[mt] = MFMA32(Wq8[mt][kt], fqh[kt], aq[mt]);
        aq[mt] = MFMA32(Wq8[mt][kt], fql[kt], aq[mt]);
      }
    }

    // ---- split q,k accumulators (energy frags, same lane) ----
    s16x4 qh[4], ql[4], kh[4], kl[4];
#pragma unroll
    for (int kt = 0; kt < 4; ++kt)
#pragma unroll
      for (int r = 0; r < 4; ++r) {
        bf16 h = (bf16)aq[kt][r];
        qh[kt][r] = (short)__builtin_bit_cast(u16, h);
        ql[kt][r] = (short)bfbits(aq[kt][r] - (float)h);
        bf16 h2 = (bf16)ak[kt][r];
        kh[kt][r] = (short)__builtin_bit_cast(u16, h2);
        kl[kt][r] = (short)bfbits(ak[kt][r] - (float)h2);
      }

    // ---- energy = q^T k ----
    f32x4 e = zero;
#pragma unroll
    for (int kt = 0; kt < 4; ++kt) {
      e = MFMA16(qh[kt], kh[kt], e);
      e = MFMA16(qh[kt], kl[kt], e);
      e = MFMA16(ql[kt], kh[kt], e);
    }

    // ---- softmax over refpix ----
#pragma unroll
    for (int r = 0; r < 4; ++r) {
      float x = e[r];
      float m = x;
      m = fmaxf(m, __shfl_xor(m, 1));
      m = fmaxf(m, __shfl_xor(m, 2));
      m = fmaxf(m, __shfl_xor(m, 4));
      m = fmaxf(m, __shfl_xor(m, 8));
      float p = __expf(x - m);
      float s = p;
      s += __shfl_xor(s, 1);
      s += __shfl_xor(s, 2);
      s += __shfl_xor(s, 4);
      s += __shfl_xor(s, 8);
      sPw[(4 * g + r) * 20 + n] = bfbits(p * __builtin_amdgcn_rcpf(s));
    }

    // ---- O tiles: A = v (same lane), B = attn^T ----
    s16x4 pa = *(const s16x4*)&sPw[n * 20 + 4 * g];
    f32x4 ao[4];
#pragma unroll
    for (int mt = 0; mt < 4; ++mt) {
      s16x4 vb;
#pragma unroll
      for (int j = 0; j < 4; ++j) vb[j] = (short)bfbits(av[mt][j]);
      ao[mt] = MFMA16(vb, pa, zero);
    }

    // ---- x = Wfc * O (K16) ----
    s16x4 ob[4];
#pragma unroll
    for (int kt = 0; kt < 4; ++kt)
#pragma unroll
      for (int j = 0; j < 4; ++j) ob[kt][j] = (short)bfbits(ao[kt][j]);
    f32x4 xa[4];
#pragma unroll
    for (int mt = 0; mt < 4; ++mt) {
      xa[mt] = zero;
#pragma unroll
      for (int kt = 0; kt < 4; ++kt)
        xa[mt] = MFMA16(Wf4[mt][kt], ob[kt], xa[mt]);
    }

    // ---- GroupNorm over 64x16 ----
    float s1 = 0.f, s2 = 0.f;
#pragma unroll
    for (int mt = 0; mt < 4; ++mt)
#pragma unroll
      for (int r = 0; r < 4; ++r) {
        float v = xa[mt][r];
        s1 += v; s2 += v * v;
      }
#pragma unroll
    for (int mask = 1; mask < 64; mask <<= 1) {
      s1 += __shfl_xor(s1, mask);
      s2 += __shfl_xor(s2, mask);
    }
    const float mean = s1 * (1.f / 1024.f);
    const float var  = s2 * (1.f / 1024.f) - mean * mean;
    const float rstd = rsqrtf(var + 1e-5f);

    // ---- affine + exact residual: RMW own-column slots of sQ[pp] ----
#pragma unroll
    for (int mt = 0; mt < 4; ++mt)
#pragma unroll
      for (int r = 0; r < 4; ++r) {
        const int row = 16 * mt + 4 * g + r;
        const int addr = row * 64 + rp * 16 + 4 * (wv ^ rp ^ ((row >> 3) & 3)) + wl;
        sQ[pp][addr] = (xa[mt][r] - mean) * rstd * sGn[row] + sGn[64 + row] + sQ[pp][addr];
      }

    // B3: staging visible to all waves
    asm volatile("s_waitcnt lgkmcnt(0)" ::: "memory");
    __builtin_amdgcn_s_barrier();
    __builtin_amdgcn_sched_barrier(0);

    // ---- cooperative coalesced store (non-temporal) ----
#pragma unroll
    for (int s = 0; s < 4; ++s) {
      f4 o = *(const f4*)&sQ[pp][lbase[s] + lane * 4];
      __builtin_nontemporal_store(o, (f4*)(out + sb + goff[s]));
    }

    pp ^= 1;
    sb = nsb;
  }
}

extern "C" void kernel_launch(void* const* d_in, const int* in_sizes, int n_in,
                              void* d_out, int out_size, void* d_ws, size_t ws_size,
                              hipStream_t stream) {
  const float* qx  = (const float*)d_in[0];
  const float* rx  = (const float*)d_in[1];
  const float* Wq  = (const float*)d_in[2];
  const float* Wk  = (const float*)d_in[3];
  const float* Wv  = (const float*)d_in[4];
  const float* Wfc = (const float*)d_in[5];
  const float* gw  = (const float*)d_in[6];
  const float* gb  = (const float*)d_in[7];
  float* out = (float*)d_out;

  prep_w<<<dim3(1), dim3(256), 0, stream>>>(Wq, Wk, Wv, Wfc);
  // 512 WGs = 2/CU; each WG streams one image row (16 strips)
  cvbt6<<<dim3(512), dim3(256), 0, stream>>>(qx, rx, gw, gb, out);
}